// Round 2
// baseline (11470.630 us; speedup 1.0000x reference)
//
#include <hip/hip_runtime.h>
#include <math.h>

#define NLAB 28000
#define NEDGE 224000

// ---------------------------------------------------------------- utils

__device__ __forceinline__ void atomAddF(float* p, float v) {
  unsafeAtomicAdd(p, v);   // gfx950: global_atomic_add_f32
}

struct RecurArgs {
  const float* gx[4];
  const float* wT[4];
  const float* bh[4];
  float* out[4];
  const int* len[4];
  int Tl[4];
  int dir[4];
};

// ---------------------------------------------------------------- embed

__global__ void embed_gather(const int* __restrict__ tok, const float* __restrict__ emb,
                             float* __restrict__ x, int rows) {
  int idx = blockIdx.x * blockDim.x + threadIdx.x;
  if (idx >= rows * 50) return;
  int r = idx / 50, c = idx - r * 50;
  *(float4*)&x[(size_t)r * 200 + c * 4] =
      *(const float4*)&emb[(size_t)tok[r] * 200 + c * 4];
}

// ---------------------------------------------------------------- whh pack [600,200] -> float4 tiles [50][600][4]
// wp4[k4*600 + g] = { w[g][4k4+0..3] }  -> lane g reads one float4, coalesced

__global__ void pack_whh(const float* __restrict__ whh, float* __restrict__ wT) {
  int idx = blockIdx.x * blockDim.x + threadIdx.x;
  if (idx >= 600 * 200) return;
  int g = idx / 200, k = idx - g * 200;
  wT[(size_t)((k >> 2) * 600 + g) * 4 + (k & 3)] = whh[idx];
}

// ---------------------------------------------------------------- GCN scatter-add (one wave per edge)

__global__ void gcn_gather(const float* __restrict__ feat, const int* __restrict__ src,
                           const int* __restrict__ dst, float* __restrict__ agg) {
  int wave = (int)((blockIdx.x * blockDim.x + threadIdx.x) >> 6);
  int lane = threadIdx.x & 63;
  if (wave >= NEDGE || lane >= 50) return;
  int s = src[wave], d = dst[wave];
  float4 v = *(const float4*)&feat[(size_t)s * 200 + lane * 4];
  float* p = &agg[(size_t)d * 200 + lane * 4];
  atomAddF(p + 0, v.x); atomAddF(p + 1, v.y);
  atomAddF(p + 2, v.z); atomAddF(p + 3, v.w);
}

// ---------------------------------------------------------------- generic C[M,N] = A[M,K] * W[N,K]^T (+bias)(+relu)

template <int RELU, int BIAS>
__global__ __launch_bounds__(256, 2) void gemm_nt(
    const float* __restrict__ A, const float* __restrict__ Wt,
    const float* __restrict__ bias, float* __restrict__ C,
    int M, int N, int K, int ldc) {
  __shared__ float As[16][68];
  __shared__ float Bs[16][68];
  int tx = threadIdx.x & 15, ty = threadIdx.x >> 4;
  int m0 = blockIdx.y * 64, n0 = blockIdx.x * 64;
  float c[4][4] = {};
  int row = threadIdx.x >> 2;
  int kk = (threadIdx.x & 3) * 4;
  for (int k0 = 0; k0 < K; k0 += 16) {
    int gk = k0 + kk;
    float a0 = 0, a1 = 0, a2 = 0, a3 = 0;
    float b0 = 0, b1 = 0, b2 = 0, b3 = 0;
    int gm = m0 + row;
    if (gm < M) {
      if (gk + 3 < K) {
        float4 v = *(const float4*)&A[(size_t)gm * K + gk];
        a0 = v.x; a1 = v.y; a2 = v.z; a3 = v.w;
      } else {
        if (gk + 0 < K) a0 = A[(size_t)gm * K + gk + 0];
        if (gk + 1 < K) a1 = A[(size_t)gm * K + gk + 1];
        if (gk + 2 < K) a2 = A[(size_t)gm * K + gk + 2];
        if (gk + 3 < K) a3 = A[(size_t)gm * K + gk + 3];
      }
    }
    int gn = n0 + row;
    if (gn < N) {
      if (gk + 3 < K) {
        float4 v = *(const float4*)&Wt[(size_t)gn * K + gk];
        b0 = v.x; b1 = v.y; b2 = v.z; b3 = v.w;
      } else {
        if (gk + 0 < K) b0 = Wt[(size_t)gn * K + gk + 0];
        if (gk + 1 < K) b1 = Wt[(size_t)gn * K + gk + 1];
        if (gk + 2 < K) b2 = Wt[(size_t)gn * K + gk + 2];
        if (gk + 3 < K) b3 = Wt[(size_t)gn * K + gk + 3];
      }
    }
    As[kk + 0][row] = a0; As[kk + 1][row] = a1; As[kk + 2][row] = a2; As[kk + 3][row] = a3;
    Bs[kk + 0][row] = b0; Bs[kk + 1][row] = b1; Bs[kk + 2][row] = b2; Bs[kk + 3][row] = b3;
    __syncthreads();
#pragma unroll
    for (int k = 0; k < 16; k++) {
      float4 a4 = *(const float4*)&As[k][ty * 4];
      float4 b4 = *(const float4*)&Bs[k][tx * 4];
      c[0][0] = fmaf(a4.x, b4.x, c[0][0]); c[0][1] = fmaf(a4.x, b4.y, c[0][1]);
      c[0][2] = fmaf(a4.x, b4.z, c[0][2]); c[0][3] = fmaf(a4.x, b4.w, c[0][3]);
      c[1][0] = fmaf(a4.y, b4.x, c[1][0]); c[1][1] = fmaf(a4.y, b4.y, c[1][1]);
      c[1][2] = fmaf(a4.y, b4.z, c[1][2]); c[1][3] = fmaf(a4.y, b4.w, c[1][3]);
      c[2][0] = fmaf(a4.z, b4.x, c[2][0]); c[2][1] = fmaf(a4.z, b4.y, c[2][1]);
      c[2][2] = fmaf(a4.z, b4.z, c[2][2]); c[2][3] = fmaf(a4.z, b4.w, c[2][3]);
      c[3][0] = fmaf(a4.w, b4.x, c[3][0]); c[3][1] = fmaf(a4.w, b4.y, c[3][1]);
      c[3][2] = fmaf(a4.w, b4.z, c[3][2]); c[3][3] = fmaf(a4.w, b4.w, c[3][3]);
    }
    __syncthreads();
  }
#pragma unroll
  for (int i = 0; i < 4; i++) {
    int gm = m0 + ty * 4 + i;
    if (gm >= M) continue;
#pragma unroll
    for (int j = 0; j < 4; j++) {
      int gn = n0 + tx * 4 + j;
      if (gn >= N) continue;
      float v = c[i][j];
      if (BIAS) v += bias[gn];
      if (RELU) v = fmaxf(v, 0.f);
      C[(size_t)gm * ldc + gn] = v;
    }
  }
}

// ---------------------------------------------------------------- GRU recurrence: one block per (branch,dir) chain

__global__ __launch_bounds__(640, 1) void gru_recur(RecurArgs a) {
  int blk = blockIdx.x;
  const float* __restrict__ gx = a.gx[blk];
  const float4* __restrict__ wp = (const float4*)a.wT[blk];
  const float* __restrict__ bh = a.bh[blk];
  float* __restrict__ outp = a.out[blk];
  const int* lenp = a.len[blk];
  int TT = a.Tl[blk];
  int bwd = a.dir[blk];
  int dirOff = bwd ? 200 : 0;

  __shared__ float h[200][4];
  __shared__ float gh[600][4];
  __shared__ float bhs[600];
  __shared__ int lens[4];
  int tid = threadIdx.x;
  for (int i = tid; i < 800; i += 640) ((float*)h)[i] = 0.f;
  for (int i = tid; i < 600; i += 640) bhs[i] = bh[i];
  if (tid < 4) lens[tid] = lenp[tid];
  __syncthreads();
  int maxlen = max(max(lens[0], lens[1]), max(lens[2], lens[3]));

  for (int s = 0; s < maxlen; s++) {
    // phase A: gh[g][b] = sum_k whh[g,k] * h[k][b]  (+bhh), float4-packed weights
    if (tid < 600) {
      float a0 = 0, a1 = 0, a2 = 0, a3 = 0;
#pragma unroll 10
      for (int k4 = 0; k4 < 50; k4++) {
        float4 w4 = wp[k4 * 600 + tid];
        float4 h0 = *(const float4*)&h[4 * k4 + 0][0];
        float4 h1 = *(const float4*)&h[4 * k4 + 1][0];
        float4 h2 = *(const float4*)&h[4 * k4 + 2][0];
        float4 h3 = *(const float4*)&h[4 * k4 + 3][0];
        a0 = fmaf(w4.x, h0.x, a0); a1 = fmaf(w4.x, h0.y, a1);
        a2 = fmaf(w4.x, h0.z, a2); a3 = fmaf(w4.x, h0.w, a3);
        a0 = fmaf(w4.y, h1.x, a0); a1 = fmaf(w4.y, h1.y, a1);
        a2 = fmaf(w4.y, h1.z, a2); a3 = fmaf(w4.y, h1.w, a3);
        a0 = fmaf(w4.z, h2.x, a0); a1 = fmaf(w4.z, h2.y, a1);
        a2 = fmaf(w4.z, h2.z, a2); a3 = fmaf(w4.z, h2.w, a3);
        a0 = fmaf(w4.w, h3.x, a0); a1 = fmaf(w4.w, h3.y, a1);
        a2 = fmaf(w4.w, h3.z, a2); a3 = fmaf(w4.w, h3.w, a3);
      }
      float bb = bhs[tid];
      gh[tid][0] = a0 + bb; gh[tid][1] = a1 + bb;
      gh[tid][2] = a2 + bb; gh[tid][3] = a3 + bb;
    }
    __syncthreads();
    // phase B: gates + h update + output write
    for (int it = tid; it < 800; it += 640) {
      int i = it >> 2, b = it & 3;
      int Lb = lens[b];
      if (s < Lb) {
        int ta = bwd ? (Lb - 1 - s) : s;
        const float* gxr = gx + (size_t)(b * TT + ta) * 600;
        float r = 1.f / (1.f + expf(-(gxr[i] + gh[i][b])));
        float z = 1.f / (1.f + expf(-(gxr[200 + i] + gh[200 + i][b])));
        float n = tanhf(gxr[400 + i] + r * gh[400 + i][b]);
        float hn = (1.f - z) * n + z * h[i][b];
        h[i][b] = hn;
        outp[(size_t)(b * TT + ta) * 400 + dirOff + i] = hn;
      }
    }
    __syncthreads();
  }
}

// ---------------------------------------------------------------- attention v2
// Block: 256 threads = 4 waves; wave w = batch b. Block covers 32 labels (n0).
// lf (label_feature) shared in LDS; x / xf1 streamed from L2 with float4 loads.
// Per-lane 4x4 register tile: lane = nq*8+tq; n = 4*nq+i, t(or d) = 4*tq+j.
// fc1 folded through PV (xf1 = out1 @ fc1^T, ld 224, cols 200..223 zeroed).

#define LFS 404   // lf row stride (pad)
#define PTS 36    // P tile row stride
#define XFS 224   // xf1 row stride

__device__ __forceinline__ void logits_tile(
    const float (&lf)[32][LFS], const float* __restrict__ xrow0,
    int nq, int tq, float (&s)[4][4]) {
#pragma unroll
  for (int i = 0; i < 4; i++)
#pragma unroll
    for (int j = 0; j < 4; j++) s[i][j] = 0.f;
  const float* xr0 = xrow0 + (size_t)(4 * tq + 0) * 400;
  const float* xr1 = xrow0 + (size_t)(4 * tq + 1) * 400;
  const float* xr2 = xrow0 + (size_t)(4 * tq + 2) * 400;
  const float* xr3 = xrow0 + (size_t)(4 * tq + 3) * 400;
#pragma unroll 2
  for (int k4 = 0; k4 < 100; k4++) {
    float4 l0 = *(const float4*)&lf[4 * nq + 0][k4 * 4];
    float4 l1 = *(const float4*)&lf[4 * nq + 1][k4 * 4];
    float4 l2 = *(const float4*)&lf[4 * nq + 2][k4 * 4];
    float4 l3 = *(const float4*)&lf[4 * nq + 3][k4 * 4];
    float4 x0 = *(const float4*)&xr0[k4 * 4];
    float4 x1 = *(const float4*)&xr1[k4 * 4];
    float4 x2 = *(const float4*)&xr2[k4 * 4];
    float4 x3 = *(const float4*)&xr3[k4 * 4];
#define DOT4(SS, LL, XX) \
    SS = fmaf(LL.x, XX.x, SS); SS = fmaf(LL.y, XX.y, SS); \
    SS = fmaf(LL.z, XX.z, SS); SS = fmaf(LL.w, XX.w, SS);
    DOT4(s[0][0], l0, x0) DOT4(s[0][1], l0, x1) DOT4(s[0][2], l0, x2) DOT4(s[0][3], l0, x3)
    DOT4(s[1][0], l1, x0) DOT4(s[1][1], l1, x1) DOT4(s[1][2], l1, x2) DOT4(s[1][3], l1, x3)
    DOT4(s[2][0], l2, x0) DOT4(s[2][1], l2, x1) DOT4(s[2][2], l2, x2) DOT4(s[2][3], l2, x3)
    DOT4(s[3][0], l3, x0) DOT4(s[3][1], l3, x1) DOT4(s[3][2], l3, x2) DOT4(s[3][3], l3, x3)
#undef DOT4
  }
}

__device__ __forceinline__ void pv_tile(
    const float (&P)[32][PTS], const float* __restrict__ xfrow0,
    int nq, int tq, float (&acc)[4][7][4]) {
#pragma unroll
  for (int db = 0; db < 7; db++) {
    int d = db * 32 + tq * 4;
    for (int t = 0; t < 32; t++) {
      float4 p = *(const float4*)&P[t][4 * nq];
      float4 v = *(const float4*)&xfrow0[(size_t)t * XFS + d];
      acc[0][db][0] = fmaf(p.x, v.x, acc[0][db][0]);
      acc[0][db][1] = fmaf(p.x, v.y, acc[0][db][1]);
      acc[0][db][2] = fmaf(p.x, v.z, acc[0][db][2]);
      acc[0][db][3] = fmaf(p.x, v.w, acc[0][db][3]);
      acc[1][db][0] = fmaf(p.y, v.x, acc[1][db][0]);
      acc[1][db][1] = fmaf(p.y, v.y, acc[1][db][1]);
      acc[1][db][2] = fmaf(p.y, v.z, acc[1][db][2]);
      acc[1][db][3] = fmaf(p.y, v.w, acc[1][db][3]);
      acc[2][db][0] = fmaf(p.z, v.x, acc[2][db][0]);
      acc[2][db][1] = fmaf(p.z, v.y, acc[2][db][1]);
      acc[2][db][2] = fmaf(p.z, v.z, acc[2][db][2]);
      acc[2][db][3] = fmaf(p.z, v.w, acc[2][db][3]);
      acc[3][db][0] = fmaf(p.w, v.x, acc[3][db][0]);
      acc[3][db][1] = fmaf(p.w, v.y, acc[3][db][1]);
      acc[3][db][2] = fmaf(p.w, v.z, acc[3][db][2]);
      acc[3][db][3] = fmaf(p.w, v.w, acc[3][db][3]);
    }
  }
}

__global__ __launch_bounds__(256, 2) void attn_v2(
    const float* __restrict__ xab, const float* __restrict__ xfab,
    const float* __restrict__ xti, const float* __restrict__ xfti,
    const float* __restrict__ lab, const float* __restrict__ gnf,
    const float* __restrict__ fc1b, const float* __restrict__ fc2w,
    const float* __restrict__ fc2b, float* __restrict__ outp) {
  __shared__ float lf[32][LFS];
  __shared__ float Pt[4][32][PTS];
  __shared__ float b1s[XFS], w2s[XFS];

  int tid = threadIdx.x;
  int n0 = blockIdx.x * 32;

  for (int u = tid; u < 3200; u += 256) {
    int n = u / 100, c = (u - n * 100) * 4;
    float4 v = (c < 200) ? *(const float4*)&lab[(size_t)(n0 + n) * 200 + c]
                         : *(const float4*)&gnf[(size_t)(n0 + n) * 200 + (c - 200)];
    *(float4*)&lf[n][c] = v;
  }
  for (int u = tid; u < XFS; u += 256) {
    b1s[u] = (u < 200) ? fc1b[u] : 0.f;
    w2s[u] = (u < 200) ? fc2w[u] : 0.f;
  }
  __syncthreads();

  int w = tid >> 6;          // batch
  int lane = tid & 63;
  int nq = lane >> 3, tq = lane & 7;
  float (&Pw)[32][PTS] = Pt[w];

  const float* xab_b = xab + (size_t)w * 384 * 400;
  const float* xfab_b = xfab + (size_t)w * 384 * XFS;
  const float* xti_b = xti + (size_t)w * 64 * 400;
  const float* xfti_b = xfti + (size_t)w * 64 * XFS;

  float acc[4][7][4];
#pragma unroll
  for (int i = 0; i < 4; i++)
#pragma unroll
    for (int db = 0; db < 7; db++)
#pragma unroll
      for (int j = 0; j < 4; j++) acc[i][db][j] = 0.f;

  // ---------------- abstract branch: online softmax over 12 tiles
  float m[4] = {-INFINITY, -INFINITY, -INFINITY, -INFINITY};
  float l[4] = {0.f, 0.f, 0.f, 0.f};
  for (int tile = 0; tile < 12; tile++) {
    int t0 = tile * 32;
    float s[4][4];
    logits_tile(lf, xab_b + (size_t)t0 * 400, nq, tq, s);
#pragma unroll
    for (int i = 0; i < 4; i++) {
      float tm = fmaxf(fmaxf(s[i][0], s[i][1]), fmaxf(s[i][2], s[i][3]));
#pragma unroll
      for (int o = 1; o <= 4; o <<= 1) tm = fmaxf(tm, __shfl_xor(tm, o));
      float mn = fmaxf(m[i], tm);
      float cr = expf(m[i] - mn);
      float ts = 0.f;
#pragma unroll
      for (int j = 0; j < 4; j++) { s[i][j] = expf(s[i][j] - mn); ts += s[i][j]; }
#pragma unroll
      for (int o = 1; o <= 4; o <<= 1) ts += __shfl_xor(ts, o);
      l[i] = l[i] * cr + ts;
      m[i] = mn;
#pragma unroll
      for (int db = 0; db < 7; db++)
#pragma unroll
        for (int j = 0; j < 4; j++) acc[i][db][j] *= cr;
    }
#pragma unroll
    for (int j = 0; j < 4; j++) {
      float4 pv = {s[0][j], s[1][j], s[2][j], s[3][j]};
      *(float4*)&Pw[4 * tq + j][4 * nq] = pv;
    }
    pv_tile(Pw, xfab_b + (size_t)t0 * XFS, nq, tq, acc);
  }
#pragma unroll
  for (int i = 0; i < 4; i++) {
    float inv = 1.f / l[i];
#pragma unroll
    for (int db = 0; db < 7; db++)
#pragma unroll
      for (int j = 0; j < 4; j++) acc[i][db][j] *= inv;
  }

  // ---------------- title branch: exact softmax over 2 tiles
  {
    float sA[4][4], sB[4][4];
    logits_tile(lf, xti_b, nq, tq, sA);
    logits_tile(lf, xti_b + (size_t)32 * 400, nq, tq, sB);
    float inv[4];
#pragma unroll
    for (int i = 0; i < 4; i++) {
      float tm = fmaxf(fmaxf(fmaxf(sA[i][0], sA[i][1]), fmaxf(sA[i][2], sA[i][3])),
                       fmaxf(fmaxf(sB[i][0], sB[i][1]), fmaxf(sB[i][2], sB[i][3])));
#pragma unroll
      for (int o = 1; o <= 4; o <<= 1) tm = fmaxf(tm, __shfl_xor(tm, o));
      float ts = 0.f;
#pragma unroll
      for (int j = 0; j < 4; j++) {
        sA[i][j] = expf(sA[i][j] - tm); ts += sA[i][j];
        sB[i][j] = expf(sB[i][j] - tm); ts += sB[i][j];
      }
#pragma unroll
      for (int o = 1; o <= 4; o <<= 1) ts += __shfl_xor(ts, o);
      inv[i] = 1.f / ts;
    }
#pragma unroll
    for (int j = 0; j < 4; j++) {
      float4 pv = {sA[0][j] * inv[0], sA[1][j] * inv[1], sA[2][j] * inv[2], sA[3][j] * inv[3]};
      *(float4*)&Pw[4 * tq + j][4 * nq] = pv;
    }
    pv_tile(Pw, xfti_b, nq, tq, acc);
#pragma unroll
    for (int j = 0; j < 4; j++) {
      float4 pv = {sB[0][j] * inv[0], sB[1][j] * inv[1], sB[2][j] * inv[2], sB[3][j] * inv[3]};
      *(float4*)&Pw[4 * tq + j][4 * nq] = pv;
    }
    pv_tile(Pw, xfti_b + (size_t)32 * XFS, nq, tq, acc);
  }

  // ---------------- epilogue: leaky(fc1) -> fc2 dot over d, reduce over tq lanes
  float fb2 = fc2b[0];
#pragma unroll
  for (int i = 0; i < 4; i++) {
    float part = 0.f;
#pragma unroll
    for (int db = 0; db < 7; db++) {
      int d = db * 32 + tq * 4;
#pragma unroll
      for (int j = 0; j < 4; j++) {
        float v = acc[i][db][j] + b1s[d + j];
        v = v >= 0.f ? v : 0.2f * v;
        part = fmaf(v, w2s[d + j], part);
      }
    }
#pragma unroll
    for (int o = 1; o <= 4; o <<= 1) part += __shfl_xor(part, o);
    if (tq == 0) {
      float v = part + fb2;
      v = v >= 0.f ? v : 0.2f * v;
      outp[(size_t)w * NLAB + n0 + 4 * nq + i] = v;
    }
  }
}

// ---------------------------------------------------------------- launch

extern "C" void kernel_launch(void* const* d_in, const int* in_sizes, int n_in,
                              void* d_out, int out_size, void* d_ws, size_t ws_size,
                              hipStream_t stream) {
  (void)in_sizes; (void)n_in; (void)out_size; (void)ws_size;
  const int* tok_ab = (const int*)d_in[0];
  const int* tok_ti = (const int*)d_in[1];
  const int* len_ab = (const int*)d_in[2];
  const int* len_ti = (const int*)d_in[3];
  const int* esrc = (const int*)d_in[4];
  const int* edst = (const int*)d_in[5];
  const float* gnf = (const float*)d_in[6];
  const float* emb = (const float*)d_in[7];
  const float* wih0f = (const float*)d_in[8],  *whh0f = (const float*)d_in[9];
  const float* bih0f = (const float*)d_in[10], *bhh0f = (const float*)d_in[11];
  const float* wih0b = (const float*)d_in[12], *whh0b = (const float*)d_in[13];
  const float* bih0b = (const float*)d_in[14], *bhh0b = (const float*)d_in[15];
  const float* wih1f = (const float*)d_in[16], *whh1f = (const float*)d_in[17];
  const float* bih1f = (const float*)d_in[18], *bhh1f = (const float*)d_in[19];
  const float* wih1b = (const float*)d_in[20], *whh1b = (const float*)d_in[21];
  const float* bih1b = (const float*)d_in[22], *bhh1b = (const float*)d_in[23];
  const float* gw1 = (const float*)d_in[24], *gb1 = (const float*)d_in[25];
  const float* gw2 = (const float*)d_in[26], *gb2 = (const float*)d_in[27];
  const float* fc1w = (const float*)d_in[28], *fc1b = (const float*)d_in[29];
  const float* fc2w = (const float*)d_in[30], *fc2b = (const float*)d_in[31];

  float* W = (float*)d_ws;
  float* agg  = W;             // 5,600,000 f  (overlaid by GRU scratch afterwards)
  float* hbuf = W + 5600000;   // 5,600,000 f
  float* lab  = W + 11200000;  // 5,600,000 f
  // overlay region (inside agg, used only after GCN is done):
  float* whhT   = W;            // 480,000
  float* x0ab   = W + 480000;   // 307,200
  float* x0ti   = W + 787200;   // 51,200
  float* gxfab  = W + 838400;   // 921,600
  float* gxbab  = W + 1760000;  // 921,600
  float* gxfti  = W + 2681600;  // 153,600
  float* gxbti  = W + 2835200;  // 153,600
  float* out0ab = W + 2988800;  // 614,400
  float* out0ti = W + 3603200;  // 102,400
  float* out1ab = W + 3705600;  // 614,400
  float* out1ti = W + 4320000;  // 102,400
  float* xf1ab  = W + 4422400;  // 344,064 (1536 x 224)
  float* xf1ti  = W + 4766464;  // 57,344  (256 x 224)

  int gatherBlocks = NEDGE / 4;  // one wave per edge, 4 waves/block
  dim3 gGcn(4, 438);             // N=200 -> 4 tiles, M=28000 -> 438 tiles

  // ---- GCN ----
  hipMemsetAsync(agg, 0, 5600000 * sizeof(float), stream);
  gcn_gather<<<gatherBlocks, 256, 0, stream>>>(gnf, esrc, edst, agg);
  gemm_nt<1, 1><<<gGcn, 256, 0, stream>>>(agg, gw1, gb1, hbuf, NLAB, 200, 200, 200);
  hipMemsetAsync(agg, 0, 5600000 * sizeof(float), stream);
  gcn_gather<<<gatherBlocks, 256, 0, stream>>>(hbuf, esrc, edst, agg);
  gemm_nt<0, 1><<<gGcn, 256, 0, stream>>>(agg, gw2, gb2, lab, NLAB, 200, 200, 200);

  // ---- GRU prep (now safe to overlay agg) ----
  pack_whh<<<(120000 + 255) / 256, 256, 0, stream>>>(whh0f, whhT + 0);
  pack_whh<<<(120000 + 255) / 256, 256, 0, stream>>>(whh0b, whhT + 120000);
  pack_whh<<<(120000 + 255) / 256, 256, 0, stream>>>(whh1f, whhT + 240000);
  pack_whh<<<(120000 + 255) / 256, 256, 0, stream>>>(whh1b, whhT + 360000);
  embed_gather<<<(1536 * 50 + 255) / 256, 256, 0, stream>>>(tok_ab, emb, x0ab, 1536);
  embed_gather<<<(256 * 50 + 255) / 256, 256, 0, stream>>>(tok_ti, emb, x0ti, 256);
  // zero out0ab..out1ti (contiguous) for padded-position zeros
  hipMemsetAsync(out0ab, 0, (size_t)1433600 * sizeof(float), stream);
  // zero xf1 (incl. pad cols 200..223)
  hipMemsetAsync(xf1ab, 0, (size_t)(344064 + 57344) * sizeof(float), stream);

  dim3 gGxAb(10, 24), gGxTi(10, 4);
  gemm_nt<0, 1><<<gGxAb, 256, 0, stream>>>(x0ab, wih0f, bih0f, gxfab, 1536, 600, 200, 600);
  gemm_nt<0, 1><<<gGxAb, 256, 0, stream>>>(x0ab, wih0b, bih0b, gxbab, 1536, 600, 200, 600);
  gemm_nt<0, 1><<<gGxTi, 256, 0, stream>>>(x0ti, wih0f, bih0f, gxfti, 256, 600, 200, 600);
  gemm_nt<0, 1><<<gGxTi, 256, 0, stream>>>(x0ti, wih0b, bih0b, gxbti, 256, 600, 200, 600);

  RecurArgs r0;
  r0.gx[0] = gxfab; r0.gx[1] = gxbab; r0.gx[2] = gxfti; r0.gx[3] = gxbti;
  r0.wT[0] = whhT; r0.wT[1] = whhT + 120000; r0.wT[2] = whhT; r0.wT[3] = whhT + 120000;
  r0.bh[0] = bhh0f; r0.bh[1] = bhh0b; r0.bh[2] = bhh0f; r0.bh[3] = bhh0b;
  r0.out[0] = out0ab; r0.out[1] = out0ab; r0.out[2] = out0ti; r0.out[3] = out0ti;
  r0.len[0] = len_ab; r0.len[1] = len_ab; r0.len[2] = len_ti; r0.len[3] = len_ti;
  r0.Tl[0] = 384; r0.Tl[1] = 384; r0.Tl[2] = 64; r0.Tl[3] = 64;
  r0.dir[0] = 0; r0.dir[1] = 1; r0.dir[2] = 0; r0.dir[3] = 1;
  gru_recur<<<4, 640, 0, stream>>>(r0);

  gemm_nt<0, 1><<<gGxAb, 256, 0, stream>>>(out0ab, wih1f, bih1f, gxfab, 1536, 600, 400, 600);
  gemm_nt<0, 1><<<gGxAb, 256, 0, stream>>>(out0ab, wih1b, bih1b, gxbab, 1536, 600, 400, 600);
  gemm_nt<0, 1><<<gGxTi, 256, 0, stream>>>(out0ti, wih1f, bih1f, gxfti, 256, 600, 400, 600);
  gemm_nt<0, 1><<<gGxTi, 256, 0, stream>>>(out0ti, wih1b, bih1b, gxbti, 256, 600, 400, 600);

  RecurArgs r1 = r0;
  r1.wT[0] = whhT + 240000; r1.wT[1] = whhT + 360000;
  r1.wT[2] = whhT + 240000; r1.wT[3] = whhT + 360000;
  r1.bh[0] = bhh1f; r1.bh[1] = bhh1b; r1.bh[2] = bhh1f; r1.bh[3] = bhh1b;
  r1.out[0] = out1ab; r1.out[1] = out1ab; r1.out[2] = out1ti; r1.out[3] = out1ti;
  gru_recur<<<4, 640, 0, stream>>>(r1);

  // ---- xf1 = out1 @ fc1_w^T (no bias; bias folded into attention epilogue) ----
  gemm_nt<0, 0><<<dim3(4, 24), 256, 0, stream>>>(out1ab, fc1w, nullptr, xf1ab, 1536, 200, 400, XFS);
  gemm_nt<0, 0><<<dim3(4, 4), 256, 0, stream>>>(out1ti, fc1w, nullptr, xf1ti, 256, 200, 400, XFS);

  // ---- fused attention + fc1 + fc2 ----
  attn_v2<<<875, 256, 0, stream>>>(
      out1ab, xf1ab, out1ti, xf1ti, lab, gnf, fc1b, fc2w, fc2b, (float*)d_out);
}

// Round 3
// 11102.425 us; speedup vs baseline: 1.0332x; 1.0332x over previous
//
#include <hip/hip_runtime.h>
#include <math.h>

#define NLAB 28000
#define NEDGE 224000
#define XFS 224

typedef _Float16 f16;
typedef _Float16 f16x8 __attribute__((ext_vector_type(8)));
typedef float f32x4 __attribute__((ext_vector_type(4)));

// ---------------------------------------------------------------- utils

__device__ __forceinline__ void atomAddF(float* p, float v) {
  unsafeAtomicAdd(p, v);
}

struct RecurArgs {
  const float* gx[4];
  const float* wT[4];
  const float* bh[4];
  float* out[4];
  const int* len[4];
  int Tl[4];
  int dir[4];
};

// ---------------------------------------------------------------- embed

__global__ void embed_gather(const int* __restrict__ tok, const float* __restrict__ emb,
                             float* __restrict__ x, int rows) {
  int idx = blockIdx.x * blockDim.x + threadIdx.x;
  if (idx >= rows * 50) return;
  int r = idx / 50, c = idx - r * 50;
  *(float4*)&x[(size_t)r * 200 + c * 4] =
      *(const float4*)&emb[(size_t)tok[r] * 200 + c * 4];
}

// ---------------------------------------------------------------- whh pack [600,200] -> float4 tiles [50][600][4]

__global__ void pack_whh(const float* __restrict__ whh, float* __restrict__ wT) {
  int idx = blockIdx.x * blockDim.x + threadIdx.x;
  if (idx >= 600 * 200) return;
  int g = idx / 200, k = idx - g * 200;
  wT[(size_t)((k >> 2) * 600 + g) * 4 + (k & 3)] = whh[idx];
}

// ---------------------------------------------------------------- GCN scatter-add

__global__ void gcn_gather(const float* __restrict__ feat, const int* __restrict__ src,
                           const int* __restrict__ dst, float* __restrict__ agg) {
  int wave = (int)((blockIdx.x * blockDim.x + threadIdx.x) >> 6);
  int lane = threadIdx.x & 63;
  if (wave >= NEDGE || lane >= 50) return;
  int s = src[wave], d = dst[wave];
  float4 v = *(const float4*)&feat[(size_t)s * 200 + lane * 4];
  float* p = &agg[(size_t)d * 200 + lane * 4];
  atomAddF(p + 0, v.x); atomAddF(p + 1, v.y);
  atomAddF(p + 2, v.z); atomAddF(p + 3, v.w);
}

// ---------------------------------------------------------------- generic C[M,N] = A[M,K] * W[N,K]^T (+bias)(+relu)

template <int RELU, int BIAS>
__global__ __launch_bounds__(256, 2) void gemm_nt(
    const float* __restrict__ A, const float* __restrict__ Wt,
    const float* __restrict__ bias, float* __restrict__ C,
    int M, int N, int K, int ldc) {
  __shared__ float As[16][68];
  __shared__ float Bs[16][68];
  int tx = threadIdx.x & 15, ty = threadIdx.x >> 4;
  int m0 = blockIdx.y * 64, n0 = blockIdx.x * 64;
  float c[4][4] = {};
  int row = threadIdx.x >> 2;
  int kk = (threadIdx.x & 3) * 4;
  for (int k0 = 0; k0 < K; k0 += 16) {
    int gk = k0 + kk;
    float a0 = 0, a1 = 0, a2 = 0, a3 = 0;
    float b0 = 0, b1 = 0, b2 = 0, b3 = 0;
    int gm = m0 + row;
    if (gm < M) {
      if (gk + 3 < K) {
        float4 v = *(const float4*)&A[(size_t)gm * K + gk];
        a0 = v.x; a1 = v.y; a2 = v.z; a3 = v.w;
      } else {
        if (gk + 0 < K) a0 = A[(size_t)gm * K + gk + 0];
        if (gk + 1 < K) a1 = A[(size_t)gm * K + gk + 1];
        if (gk + 2 < K) a2 = A[(size_t)gm * K + gk + 2];
        if (gk + 3 < K) a3 = A[(size_t)gm * K + gk + 3];
      }
    }
    int gn = n0 + row;
    if (gn < N) {
      if (gk + 3 < K) {
        float4 v = *(const float4*)&Wt[(size_t)gn * K + gk];
        b0 = v.x; b1 = v.y; b2 = v.z; b3 = v.w;
      } else {
        if (gk + 0 < K) b0 = Wt[(size_t)gn * K + gk + 0];
        if (gk + 1 < K) b1 = Wt[(size_t)gn * K + gk + 1];
        if (gk + 2 < K) b2 = Wt[(size_t)gn * K + gk + 2];
        if (gk + 3 < K) b3 = Wt[(size_t)gn * K + gk + 3];
      }
    }
    As[kk + 0][row] = a0; As[kk + 1][row] = a1; As[kk + 2][row] = a2; As[kk + 3][row] = a3;
    Bs[kk + 0][row] = b0; Bs[kk + 1][row] = b1; Bs[kk + 2][row] = b2; Bs[kk + 3][row] = b3;
    __syncthreads();
#pragma unroll
    for (int k = 0; k < 16; k++) {
      float4 a4 = *(const float4*)&As[k][ty * 4];
      float4 b4 = *(const float4*)&Bs[k][tx * 4];
      c[0][0] = fmaf(a4.x, b4.x, c[0][0]); c[0][1] = fmaf(a4.x, b4.y, c[0][1]);
      c[0][2] = fmaf(a4.x, b4.z, c[0][2]); c[0][3] = fmaf(a4.x, b4.w, c[0][3]);
      c[1][0] = fmaf(a4.y, b4.x, c[1][0]); c[1][1] = fmaf(a4.y, b4.y, c[1][1]);
      c[1][2] = fmaf(a4.y, b4.z, c[1][2]); c[1][3] = fmaf(a4.y, b4.w, c[1][3]);
      c[2][0] = fmaf(a4.z, b4.x, c[2][0]); c[2][1] = fmaf(a4.z, b4.y, c[2][1]);
      c[2][2] = fmaf(a4.z, b4.z, c[2][2]); c[2][3] = fmaf(a4.z, b4.w, c[2][3]);
      c[3][0] = fmaf(a4.w, b4.x, c[3][0]); c[3][1] = fmaf(a4.w, b4.y, c[3][1]);
      c[3][2] = fmaf(a4.w, b4.z, c[3][2]); c[3][3] = fmaf(a4.w, b4.w, c[3][3]);
    }
    __syncthreads();
  }
#pragma unroll
  for (int i = 0; i < 4; i++) {
    int gm = m0 + ty * 4 + i;
    if (gm >= M) continue;
#pragma unroll
    for (int j = 0; j < 4; j++) {
      int gn = n0 + tx * 4 + j;
      if (gn >= N) continue;
      float v = c[i][j];
      if (BIAS) v += bias[gn];
      if (RELU) v = fmaxf(v, 0.f);
      C[(size_t)gm * ldc + gn] = v;
    }
  }
}

// ---------------------------------------------------------------- GRU recurrence (k4 0..27 register-cached)

__global__ __launch_bounds__(640, 2) void gru_recur(RecurArgs a) {
  int blk = blockIdx.x;
  const float* __restrict__ gx = a.gx[blk];
  const float4* __restrict__ wp = (const float4*)a.wT[blk];
  const float* __restrict__ bh = a.bh[blk];
  float* __restrict__ outp = a.out[blk];
  const int* lenp = a.len[blk];
  int TT = a.Tl[blk];
  int bwd = a.dir[blk];
  int dirOff = bwd ? 200 : 0;

  __shared__ float h[200][4];
  __shared__ float gh[600][4];
  __shared__ float bhs[600];
  __shared__ int lens[4];
  int tid = threadIdx.x;
  for (int i = tid; i < 800; i += 640) ((float*)h)[i] = 0.f;
  for (int i = tid; i < 600; i += 640) bhs[i] = bh[i];
  if (tid < 4) lens[tid] = lenp[tid];

  float4 wreg[28];
  if (tid < 600) {
#pragma unroll
    for (int k4 = 0; k4 < 28; k4++) wreg[k4] = wp[k4 * 600 + tid];
  }
  __syncthreads();
  int maxlen = max(max(lens[0], lens[1]), max(lens[2], lens[3]));

  for (int s = 0; s < maxlen; s++) {
    if (tid < 600) {
      float a0 = 0, a1 = 0, a2 = 0, a3 = 0;
#pragma unroll
      for (int k4 = 0; k4 < 28; k4++) {
        float4 w4 = wreg[k4];
        float4 h0 = *(const float4*)&h[4 * k4 + 0][0];
        float4 h1 = *(const float4*)&h[4 * k4 + 1][0];
        float4 h2 = *(const float4*)&h[4 * k4 + 2][0];
        float4 h3 = *(const float4*)&h[4 * k4 + 3][0];
        a0 = fmaf(w4.x, h0.x, a0); a1 = fmaf(w4.x, h0.y, a1);
        a2 = fmaf(w4.x, h0.z, a2); a3 = fmaf(w4.x, h0.w, a3);
        a0 = fmaf(w4.y, h1.x, a0); a1 = fmaf(w4.y, h1.y, a1);
        a2 = fmaf(w4.y, h1.z, a2); a3 = fmaf(w4.y, h1.w, a3);
        a0 = fmaf(w4.z, h2.x, a0); a1 = fmaf(w4.z, h2.y, a1);
        a2 = fmaf(w4.z, h2.z, a2); a3 = fmaf(w4.z, h2.w, a3);
        a0 = fmaf(w4.w, h3.x, a0); a1 = fmaf(w4.w, h3.y, a1);
        a2 = fmaf(w4.w, h3.z, a2); a3 = fmaf(w4.w, h3.w, a3);
      }
#pragma unroll 11
      for (int k4 = 28; k4 < 50; k4++) {
        float4 w4 = wp[k4 * 600 + tid];
        float4 h0 = *(const float4*)&h[4 * k4 + 0][0];
        float4 h1 = *(const float4*)&h[4 * k4 + 1][0];
        float4 h2 = *(const float4*)&h[4 * k4 + 2][0];
        float4 h3 = *(const float4*)&h[4 * k4 + 3][0];
        a0 = fmaf(w4.x, h0.x, a0); a1 = fmaf(w4.x, h0.y, a1);
        a2 = fmaf(w4.x, h0.z, a2); a3 = fmaf(w4.x, h0.w, a3);
        a0 = fmaf(w4.y, h1.x, a0); a1 = fmaf(w4.y, h1.y, a1);
        a2 = fmaf(w4.y, h1.z, a2); a3 = fmaf(w4.y, h1.w, a3);
        a0 = fmaf(w4.z, h2.x, a0); a1 = fmaf(w4.z, h2.y, a1);
        a2 = fmaf(w4.z, h2.z, a2); a3 = fmaf(w4.z, h2.w, a3);
        a0 = fmaf(w4.w, h3.x, a0); a1 = fmaf(w4.w, h3.y, a1);
        a2 = fmaf(w4.w, h3.z, a2); a3 = fmaf(w4.w, h3.w, a3);
      }
      float bb = bhs[tid];
      gh[tid][0] = a0 + bb; gh[tid][1] = a1 + bb;
      gh[tid][2] = a2 + bb; gh[tid][3] = a3 + bb;
    }
    __syncthreads();
    for (int it = tid; it < 800; it += 640) {
      int i = it >> 2, b = it & 3;
      int Lb = lens[b];
      if (s < Lb) {
        int ta = bwd ? (Lb - 1 - s) : s;
        const float* gxr = gx + (size_t)(b * TT + ta) * 600;
        float r = 1.f / (1.f + expf(-(gxr[i] + gh[i][b])));
        float z = 1.f / (1.f + expf(-(gxr[200 + i] + gh[200 + i][b])));
        float n = tanhf(gxr[400 + i] + r * gh[400 + i][b]);
        float hn = (1.f - z) * n + z * h[i][b];
        h[i][b] = hn;
        outp[(size_t)(b * TT + ta) * 400 + dirOff + i] = hn;
      }
    }
    __syncthreads();
  }
}

// ---------------------------------------------------------------- f16 fragment prep kernels
// Fragment layout (1KB block = 16(m|n) x 32k f16): lane l holds 8 elems at byte l*16.
// elem j: mn = l&15, k = (l>>4)*4 + (j&3) + (j>>2)*16.  Same formula used for all
// operands => k-slot pairing is consistent A vs B (permutation-invariant dot).

__global__ void cvt_lf_frags(const float* __restrict__ lab, const float* __restrict__ gnf,
                             f16* __restrict__ out) {
  int e = blockIdx.x * 256 + threadIdx.x;
  if (e >= 1752 * 13 * 512) return;
  int frag = e >> 9, r = e & 511;
  int l = r >> 3, j = r & 7;
  int nsub = frag / 13, kt = frag - nsub * 13;
  int label = nsub * 16 + (l & 15);
  int k = kt * 32 + ((l >> 4) << 2) + (j & 3) + ((j >> 2) << 4);
  float v = 0.f;
  if (label < NLAB && k < 400)
    v = (k < 200) ? lab[(size_t)label * 200 + k] : gnf[(size_t)label * 200 + k - 200];
  out[e] = (f16)v;
}

__global__ void cvt_x_frags(const float* __restrict__ x, f16* __restrict__ out, int TT) {
  int e = blockIdx.x * 256 + threadIdx.x;
  if (e >= 4 * TT * 13 * 512) return;
  int frag = e >> 9, r = e & 511;
  int l = r >> 3, j = r & 7;
  int kt = frag % 13, bt = frag / 13;
  int tt = bt % TT, b = bt / TT;
  int t = tt * 16 + (l & 15);
  int k = kt * 32 + ((l >> 4) << 2) + (j & 3) + ((j >> 2) << 4);
  float v = (k < 400) ? x[((size_t)b * TT * 16 + t) * 400 + k] : 0.f;
  out[e] = (f16)v;
}

__global__ void cvt_v_frags(const float* __restrict__ xf, f16* __restrict__ out, int KT) {
  int e = blockIdx.x * 256 + threadIdx.x;
  if (e >= 4 * KT * 13 * 2 * 512) return;
  int idx = e >> 9, r = e & 511;
  int l = r >> 3, j = r & 7;
  int hl = idx & 1, rest = idx >> 1;
  int dt = rest % 13, rest2 = rest / 13;
  int kt = rest2 % KT, b = rest2 / KT;
  int t = kt * 32 + ((l >> 4) << 2) + (j & 3) + ((j >> 2) << 4);
  int d = dt * 16 + (l & 15);
  float v = xf[((size_t)b * KT * 32 + t) * XFS + d];
  float hi = (float)(f16)v;
  out[e] = hl ? (f16)((v - hi) * 2048.f) : (f16)v;
}

// ---------------------------------------------------------------- MFMA attention + fc1 + fc2
// Block 256thr = 4 waves = (nh 0..1, hl 0..1); block covers 64 labels, one batch.
// hl splits: logits t-subtiles AND the V hi/lo precision split (lo scaled x2048).
// ab chunks 0..5 online-softmax (unnormalized acc, CR rescale); ti chunk 6 exact.

__global__ __launch_bounds__(256, 2) void attn_mfma(
    const f16* __restrict__ lfF, const f16* __restrict__ xFab, const f16* __restrict__ xFti,
    const f16* __restrict__ vFab, const f16* __restrict__ vFti,
    const float* __restrict__ fc1b, const float* __restrict__ fc2w,
    const float* __restrict__ fc2b, float* __restrict__ outp) {
  __shared__ float SB[2][32][65];
  __shared__ float CRS[2][2][16];
  __shared__ float LIS[2][2][16];

  int tid = threadIdx.x, lane = tid & 63, w = tid >> 6;
  int nh = w >> 1, hl = w & 1;
  int b = blockIdx.y, nt = blockIdx.x;
  int l15 = lane & 15, lg = lane >> 4;

  f32x4 acc[2][13];
#pragma unroll
  for (int ns = 0; ns < 2; ns++)
#pragma unroll
    for (int dt = 0; dt < 13; dt++) acc[ns][dt] = (f32x4){0.f, 0.f, 0.f, 0.f};
  float mrun[4] = {-INFINITY, -INFINITY, -INFINITY, -INFINITY};
  float lrun[4] = {0.f, 0.f, 0.f, 0.f};

  for (int c = 0; c < 7; c++) {
    const bool ti = (c == 6);
    const f16* xb = ti ? xFti + (size_t)b * (4 * 13 * 512)
                       : xFab + ((size_t)(b * 24 + c * 4)) * 13 * 512;
    // ---- logits: this wave covers ns 0..1  x  tsub {2hl, 2hl+1}
    f32x4 S[2][2];
#pragma unroll
    for (int ns = 0; ns < 2; ns++)
#pragma unroll
      for (int ts = 0; ts < 2; ts++) S[ns][ts] = (f32x4){0.f, 0.f, 0.f, 0.f};
#pragma unroll
    for (int kh = 0; kh < 2; kh++) {
      const int kt0 = kh ? 7 : 0;
      const int ktn = kh ? 6 : 7;
      f16x8 la[2][7];
#pragma unroll
      for (int ns = 0; ns < 2; ns++) {
        const f16* lp = lfF + (((size_t)(nt * 4 + nh * 2 + ns)) * 13 + kt0) * 512 + lane * 8;
#pragma unroll
        for (int k = 0; k < 7; k++)
          if (k < ktn) la[ns][k] = *(const f16x8*)(lp + (size_t)k * 512);
      }
#pragma unroll
      for (int ts = 0; ts < 2; ts++) {
        const f16* xp = xb + (((size_t)(hl * 2 + ts)) * 13 + kt0) * 512 + lane * 8;
        f16x8 xa[7];
#pragma unroll
        for (int k = 0; k < 7; k++)
          if (k < ktn) xa[k] = *(const f16x8*)(xp + (size_t)k * 512);
#pragma unroll
        for (int ns = 0; ns < 2; ns++)
#pragma unroll
          for (int k = 0; k < 7; k++)
            if (k < ktn)
              S[ns][ts] = __builtin_amdgcn_mfma_f32_16x16x32_f16(la[ns][k], xa[k], S[ns][ts], 0, 0, 0);
      }
    }
    __syncthreads();  // SB free from previous chunk
#pragma unroll
    for (int ns = 0; ns < 2; ns++)
#pragma unroll
      for (int ts = 0; ts < 2; ts++)
#pragma unroll
        for (int r = 0; r < 4; r++)
          SB[nh][ns * 16 + lg * 4 + r][(hl * 2 + ts) * 16 + l15] = S[ns][ts][r];
    __syncthreads();
    // ---- softmax for ns == hl labels
    {
      float vv[4][4];
#pragma unroll
      for (int r = 0; r < 4; r++)
#pragma unroll
        for (int ts = 0; ts < 4; ts++)
          vv[r][ts] = SB[nh][hl * 16 + lg * 4 + r][ts * 16 + l15];
#pragma unroll
      for (int r = 0; r < 4; r++) {
        float tm = fmaxf(fmaxf(vv[r][0], vv[r][1]), fmaxf(vv[r][2], vv[r][3]));
        tm = fmaxf(tm, __shfl_xor(tm, 1));
        tm = fmaxf(tm, __shfl_xor(tm, 2));
        tm = fmaxf(tm, __shfl_xor(tm, 4));
        tm = fmaxf(tm, __shfl_xor(tm, 8));
        if (!ti) {
          float mn = fmaxf(mrun[r], tm);
          float cr = expf(mrun[r] - mn);
          float s = 0.f;
#pragma unroll
          for (int ts = 0; ts < 4; ts++) { vv[r][ts] = expf(vv[r][ts] - mn); s += vv[r][ts]; }
          s += __shfl_xor(s, 1); s += __shfl_xor(s, 2);
          s += __shfl_xor(s, 4); s += __shfl_xor(s, 8);
          lrun[r] = lrun[r] * cr + s;
          mrun[r] = mn;
#pragma unroll
          for (int ts = 0; ts < 4; ts++)
            SB[nh][hl * 16 + lg * 4 + r][ts * 16 + l15] = vv[r][ts];
          if (l15 == 0) {
            CRS[nh][hl][lg * 4 + r] = cr;
            if (c == 5) LIS[nh][hl][lg * 4 + r] = 1.f / lrun[r];
          }
        } else {
          float s = 0.f;
#pragma unroll
          for (int ts = 0; ts < 4; ts++) { vv[r][ts] = expf(vv[r][ts] - tm); s += vv[r][ts]; }
          s += __shfl_xor(s, 1); s += __shfl_xor(s, 2);
          s += __shfl_xor(s, 4); s += __shfl_xor(s, 8);
          float inv = 1.f / s;
#pragma unroll
          for (int ts = 0; ts < 4; ts++)
            SB[nh][hl * 16 + lg * 4 + r][ts * 16 + l15] = vv[r][ts] * inv;
        }
      }
    }
    __syncthreads();
    // ---- rescale acc
    if (!ti) {
#pragma unroll
      for (int ns = 0; ns < 2; ns++)
#pragma unroll
        for (int r = 0; r < 4; r++) {
          float cr = CRS[nh][ns][lg * 4 + r];
#pragma unroll
          for (int dt = 0; dt < 13; dt++) acc[ns][dt][r] *= cr;
        }
    } else {
#pragma unroll
      for (int ns = 0; ns < 2; ns++)
#pragma unroll
        for (int r = 0; r < 4; r++) {
          float li = LIS[nh][ns][lg * 4 + r];
#pragma unroll
          for (int dt = 0; dt < 13; dt++) acc[ns][dt][r] *= li;
        }
    }
    // ---- P fragments (A operand of PV)
    f16x8 pf[2][2];
#pragma unroll
    for (int ns = 0; ns < 2; ns++)
#pragma unroll
      for (int kt = 0; kt < 2; kt++)
#pragma unroll
        for (int j = 0; j < 8; j++) {
          int col = kt * 32 + (lg << 2) + (j & 3) + ((j >> 2) << 4);
          pf[ns][kt][j] = (f16)SB[nh][ns * 16 + l15][col];
        }
    // ---- PV
#pragma unroll
    for (int dt = 0; dt < 13; dt++)
#pragma unroll
      for (int kt = 0; kt < 2; kt++) {
        const f16* vp = (ti ? vFti + (((size_t)((b * 2 + kt) * 13 + dt)) * 2 + hl) * 512
                            : vFab + (((size_t)((b * 12 + c * 2 + kt) * 13 + dt)) * 2 + hl) * 512)
                        + lane * 8;
        f16x8 vf = *(const f16x8*)vp;
#pragma unroll
        for (int ns = 0; ns < 2; ns++)
          acc[ns][dt] = __builtin_amdgcn_mfma_f32_16x16x32_f16(pf[ns][kt], vf, acc[ns][dt], 0, 0, 0);
      }
  }

  // ---- epilogue: merge hi/lo waves, fc1 bias + leaky, fc2 dot
  float part[2][4] = {{0.f, 0.f, 0.f, 0.f}, {0.f, 0.f, 0.f, 0.f}};
#pragma unroll
  for (int p = 0; p < 4; p++) {
    const int dt0 = p * 4;
    const int dtn = (p == 3) ? 1 : 4;
    __syncthreads();
    if (hl) {
#pragma unroll
      for (int ns = 0; ns < 2; ns++)
#pragma unroll
        for (int q = 0; q < 4; q++)
          if (q < dtn)
#pragma unroll
            for (int r = 0; r < 4; r++)
              SB[nh][ns * 16 + lg * 4 + r][q * 16 + l15] = acc[ns][dt0 + q][r];
    }
    __syncthreads();
    if (!hl) {
#pragma unroll
      for (int ns = 0; ns < 2; ns++)
#pragma unroll
        for (int q = 0; q < 4; q++)
          if (q < dtn)
#pragma unroll
            for (int r = 0; r < 4; r++) {
              int d = (dt0 + q) * 16 + l15;
              float y = acc[ns][dt0 + q][r] +
                        SB[nh][ns * 16 + lg * 4 + r][q * 16 + l15] * (1.f / 2048.f);
              if (d < 200) {
                y += fc1b[d];
                y = y >= 0.f ? y : 0.2f * y;
                part[ns][r] = fmaf(y, fc2w[d], part[ns][r]);
              }
            }
    }
  }
  if (!hl) {
#pragma unroll
    for (int ns = 0; ns < 2; ns++)
#pragma unroll
      for (int r = 0; r < 4; r++) {
        float s = part[ns][r];
        s += __shfl_xor(s, 1); s += __shfl_xor(s, 2);
        s += __shfl_xor(s, 4); s += __shfl_xor(s, 8);
        part[ns][r] = s;
      }
    if (l15 == 0) {
      float f2b = fc2b[0];
#pragma unroll
      for (int ns = 0; ns < 2; ns++)
#pragma unroll
        for (int r = 0; r < 4; r++) {
          int label = nt * 64 + nh * 32 + ns * 16 + lg * 4 + r;
          if (label < NLAB) {
            float y = part[ns][r] + f2b;
            y = y >= 0.f ? y : 0.2f * y;
            outp[(size_t)b * NLAB + label] = y;
          }
        }
    }
  }
}

// ---------------------------------------------------------------- launch

extern "C" void kernel_launch(void* const* d_in, const int* in_sizes, int n_in,
                              void* d_out, int out_size, void* d_ws, size_t ws_size,
                              hipStream_t stream) {
  (void)in_sizes; (void)n_in; (void)out_size; (void)ws_size;
  const int* tok_ab = (const int*)d_in[0];
  const int* tok_ti = (const int*)d_in[1];
  const int* len_ab = (const int*)d_in[2];
  const int* len_ti = (const int*)d_in[3];
  const int* esrc = (const int*)d_in[4];
  const int* edst = (const int*)d_in[5];
  const float* gnf = (const float*)d_in[6];
  const float* emb = (const float*)d_in[7];
  const float* wih0f = (const float*)d_in[8],  *whh0f = (const float*)d_in[9];
  const float* bih0f = (const float*)d_in[10], *bhh0f = (const float*)d_in[11];
  const float* wih0b = (const float*)d_in[12], *whh0b = (const float*)d_in[13];
  const float* bih0b = (const float*)d_in[14], *bhh0b = (const float*)d_in[15];
  const float* wih1f = (const float*)d_in[16], *whh1f = (const float*)d_in[17];
  const float* bih1f = (const float*)d_in[18], *bhh1f = (const float*)d_in[19];
  const float* wih1b = (const float*)d_in[20], *whh1b = (const float*)d_in[21];
  const float* bih1b = (const float*)d_in[22], *bhh1b = (const float*)d_in[23];
  const float* gw1 = (const float*)d_in[24], *gb1 = (const float*)d_in[25];
  const float* gw2 = (const float*)d_in[26], *gb2 = (const float*)d_in[27];
  const float* fc1w = (const float*)d_in[28], *fc1b = (const float*)d_in[29];
  const float* fc2w = (const float*)d_in[30], *fc2b = (const float*)d_in[31];

  float* W = (float*)d_ws;
  float* agg  = W;             // [0 .. 5.6M)
  float* hbuf = W + 5600000;   // [5.6M .. 11.2M)   dead after GCN
  float* lab  = W + 11200000;  // [11.2M .. 16.8M)
  // overlay (dead-GCN regions):
  float* whhT   = W;            // 480,000
  float* x0ab   = W + 480000;   // 307,200
  float* x0ti   = W + 787200;   // 51,200
  float* gxfab  = W + 838400;   // 921,600 (later: frag arrays)
  float* gxbab  = W + 1760000;  // 921,600
  float* gxfti  = W + 2681600;  // 153,600
  float* gxbti  = W + 2835200;  // 153,600
  float* out0ab = W + 2988800;  // 614,400
  float* out0ti = W + 3603200;  // 102,400
  float* out1ab = W + 3705600;  // 614,400
  float* out1ti = W + 4320000;  // 102,400
  float* xf1ab  = W + 4422400;  // 344,064 (1536 x 224)
  float* xf1ti  = W + 4766464;  // 57,344  (256 x 224)
  // f16 fragment arrays (counts in f32 slots; 2 f16 per slot)
  f16* xFab = (f16*)(W + 838400);    // 638,976 f16 -> 319,488 slots (overlays gx, post-GRU)
  f16* xFti = (f16*)(W + 1157888);   // 106,496 f16 ->  53,248
  f16* vFab = (f16*)(W + 1211136);   // 638,976 f16 -> 319,488
  f16* vFti = (f16*)(W + 1530624);   // 106,496 f16 ->  53,248
  f16* lfF  = (f16*)(W + 4850000);   // 11,661,312 f16 -> 5,830,656 (overlays agg tail + hbuf)

  int gatherBlocks = NEDGE / 4;
  dim3 gGcn(4, 438);

  // ---- GCN ----
  hipMemsetAsync(agg, 0, 5600000 * sizeof(float), stream);
  gcn_gather<<<gatherBlocks, 256, 0, stream>>>(gnf, esrc, edst, agg);
  gemm_nt<1, 1><<<gGcn, 256, 0, stream>>>(agg, gw1, gb1, hbuf, NLAB, 200, 200, 200);
  hipMemsetAsync(agg, 0, 5600000 * sizeof(float), stream);
  gcn_gather<<<gatherBlocks, 256, 0, stream>>>(hbuf, esrc, edst, agg);
  gemm_nt<0, 1><<<gGcn, 256, 0, stream>>>(agg, gw2, gb2, lab, NLAB, 200, 200, 200);

  // ---- label-feature fragments (hbuf dead from here) ----
  cvt_lf_frags<<<(1752 * 13 * 512 + 255) / 256, 256, 0, stream>>>(lab, gnf, lfF);

  // ---- GRU prep ----
  pack_whh<<<(120000 + 255) / 256, 256, 0, stream>>>(whh0f, whhT + 0);
  pack_whh<<<(120000 + 255) / 256, 256, 0, stream>>>(whh0b, whhT + 120000);
  pack_whh<<<(120000 + 255) / 256, 256, 0, stream>>>(whh1f, whhT + 240000);
  pack_whh<<<(120000 + 255) / 256, 256, 0, stream>>>(whh1b, whhT + 360000);
  embed_gather<<<(1536 * 50 + 255) / 256, 256, 0, stream>>>(tok_ab, emb, x0ab, 1536);
  embed_gather<<<(256 * 50 + 255) / 256, 256, 0, stream>>>(tok_ti, emb, x0ti, 256);
  hipMemsetAsync(out0ab, 0, (size_t)1433600 * sizeof(float), stream);
  hipMemsetAsync(xf1ab, 0, (size_t)(344064 + 57344) * sizeof(float), stream);

  dim3 gGxAb(10, 24), gGxTi(10, 4);
  gemm_nt<0, 1><<<gGxAb, 256, 0, stream>>>(x0ab, wih0f, bih0f, gxfab, 1536, 600, 200, 600);
  gemm_nt<0, 1><<<gGxAb, 256, 0, stream>>>(x0ab, wih0b, bih0b, gxbab, 1536, 600, 200, 600);
  gemm_nt<0, 1><<<gGxTi, 256, 0, stream>>>(x0ti, wih0f, bih0f, gxfti, 256, 600, 200, 600);
  gemm_nt<0, 1><<<gGxTi, 256, 0, stream>>>(x0ti, wih0b, bih0b, gxbti, 256, 600, 200, 600);

  RecurArgs r0;
  r0.gx[0] = gxfab; r0.gx[1] = gxbab; r0.gx[2] = gxfti; r0.gx[3] = gxbti;
  r0.wT[0] = whhT; r0.wT[1] = whhT + 120000; r0.wT[2] = whhT; r0.wT[3] = whhT + 120000;
  r0.bh[0] = bhh0f; r0.bh[1] = bhh0b; r0.bh[2] = bhh0f; r0.bh[3] = bhh0b;
  r0.out[0] = out0ab; r0.out[1] = out0ab; r0.out[2] = out0ti; r0.out[3] = out0ti;
  r0.len[0] = len_ab; r0.len[1] = len_ab; r0.len[2] = len_ti; r0.len[3] = len_ti;
  r0.Tl[0] = 384; r0.Tl[1] = 384; r0.Tl[2] = 64; r0.Tl[3] = 64;
  r0.dir[0] = 0; r0.dir[1] = 1; r0.dir[2] = 0; r0.dir[3] = 1;
  gru_recur<<<4, 640, 0, stream>>>(r0);

  gemm_nt<0, 1><<<gGxAb, 256, 0, stream>>>(out0ab, wih1f, bih1f, gxfab, 1536, 600, 400, 600);
  gemm_nt<0, 1><<<gGxAb, 256, 0, stream>>>(out0ab, wih1b, bih1b, gxbab, 1536, 600, 400, 600);
  gemm_nt<0, 1><<<gGxTi, 256, 0, stream>>>(out0ti, wih1f, bih1f, gxfti, 256, 600, 400, 600);
  gemm_nt<0, 1><<<gGxTi, 256, 0, stream>>>(out0ti, wih1b, bih1b, gxbti, 256, 600, 400, 600);

  RecurArgs r1 = r0;
  r1.wT[0] = whhT + 240000; r1.wT[1] = whhT + 360000;
  r1.wT[2] = whhT + 240000; r1.wT[3] = whhT + 360000;
  r1.bh[0] = bhh1f; r1.bh[1] = bhh1b; r1.bh[2] = bhh1f; r1.bh[3] = bhh1b;
  r1.out[0] = out1ab; r1.out[1] = out1ab; r1.out[2] = out1ti; r1.out[3] = out1ti;
  gru_recur<<<4, 640, 0, stream>>>(r1);

  // ---- xf1 = out1 @ fc1^T ----
  gemm_nt<0, 0><<<dim3(4, 24), 256, 0, stream>>>(out1ab, fc1w, nullptr, xf1ab, 1536, 200, 400, XFS);
  gemm_nt<0, 0><<<dim3(4, 4), 256, 0, stream>>>(out1ti, fc1w, nullptr, xf1ti, 256, 200, 400, XFS);

  // ---- x / V fragments (gx regions dead from here) ----
  cvt_x_frags<<<(4 * 24 * 13 * 512 + 255) / 256, 256, 0, stream>>>(out1ab, xFab, 24);
  cvt_x_frags<<<(4 * 4 * 13 * 512 + 255) / 256, 256, 0, stream>>>(out1ti, xFti, 4);
  cvt_v_frags<<<(4 * 12 * 13 * 2 * 512 + 255) / 256, 256, 0, stream>>>(xf1ab, vFab, 12);
  cvt_v_frags<<<(4 * 2 * 13 * 2 * 512 + 255) / 256, 256, 0, stream>>>(xf1ti, vFti, 2);

  // ---- fused MFMA attention ----
  attn_mfma<<<dim3(438, 4), 256, 0, stream>>>(
      lfF, xFab, xFti, vFab, vFti, fc1b, fc2w, fc2b, (float*)d_out);
}

// Round 4
// 9447.313 us; speedup vs baseline: 1.2142x; 1.1752x over previous
//
#include <hip/hip_runtime.h>
#include <math.h>

#define NLAB 28000
#define NEDGE 224000
#define XFS 224

typedef _Float16 f16;
typedef _Float16 f16x8 __attribute__((ext_vector_type(8)));
typedef float f32x4 __attribute__((ext_vector_type(4)));

// ---------------------------------------------------------------- utils

__device__ __forceinline__ void atomAddF(float* p, float v) {
  unsafeAtomicAdd(p, v);
}

struct RecurArgs {
  const float* gx[4];
  const float* wT[4];
  const float* bh[4];
  float* out[4];
  const int* len[4];
  int Tl[4];
  int dir[4];
};

// ---------------------------------------------------------------- embed

__global__ void embed_gather(const int* __restrict__ tok, const float* __restrict__ emb,
                             float* __restrict__ x, int rows) {
  int idx = blockIdx.x * blockDim.x + threadIdx.x;
  if (idx >= rows * 50) return;
  int r = idx / 50, c = idx - r * 50;
  *(float4*)&x[(size_t)r * 200 + c * 4] =
      *(const float4*)&emb[(size_t)tok[r] * 200 + c * 4];
}

// ---------------------------------------------------------------- whh pack [600,200] -> float4 tiles [50][600][4]

__global__ void pack_whh(const float* __restrict__ whh, float* __restrict__ wT) {
  int idx = blockIdx.x * blockDim.x + threadIdx.x;
  if (idx >= 600 * 200) return;
  int g = idx / 200, k = idx - g * 200;
  wT[(size_t)((k >> 2) * 600 + g) * 4 + (k & 3)] = whh[idx];
}

// ---------------------------------------------------------------- GCN scatter-add

__global__ void gcn_gather(const float* __restrict__ feat, const int* __restrict__ src,
                           const int* __restrict__ dst, float* __restrict__ agg) {
  int wave = (int)((blockIdx.x * blockDim.x + threadIdx.x) >> 6);
  int lane = threadIdx.x & 63;
  if (wave >= NEDGE || lane >= 50) return;
  int s = src[wave], d = dst[wave];
  float4 v = *(const float4*)&feat[(size_t)s * 200 + lane * 4];
  float* p = &agg[(size_t)d * 200 + lane * 4];
  atomAddF(p + 0, v.x); atomAddF(p + 1, v.y);
  atomAddF(p + 2, v.z); atomAddF(p + 3, v.w);
}

// ---------------------------------------------------------------- generic C[M,N] = A[M,K] * W[N,K]^T (+bias)(+relu)

template <int RELU, int BIAS>
__global__ __launch_bounds__(256, 2) void gemm_nt(
    const float* __restrict__ A, const float* __restrict__ Wt,
    const float* __restrict__ bias, float* __restrict__ C,
    int M, int N, int K, int ldc) {
  __shared__ float As[16][68];
  __shared__ float Bs[16][68];
  int tx = threadIdx.x & 15, ty = threadIdx.x >> 4;
  int m0 = blockIdx.y * 64, n0 = blockIdx.x * 64;
  float c[4][4] = {};
  int row = threadIdx.x >> 2;
  int kk = (threadIdx.x & 3) * 4;
  for (int k0 = 0; k0 < K; k0 += 16) {
    int gk = k0 + kk;
    float a0 = 0, a1 = 0, a2 = 0, a3 = 0;
    float b0 = 0, b1 = 0, b2 = 0, b3 = 0;
    int gm = m0 + row;
    if (gm < M) {
      if (gk + 3 < K) {
        float4 v = *(const float4*)&A[(size_t)gm * K + gk];
        a0 = v.x; a1 = v.y; a2 = v.z; a3 = v.w;
      } else {
        if (gk + 0 < K) a0 = A[(size_t)gm * K + gk + 0];
        if (gk + 1 < K) a1 = A[(size_t)gm * K + gk + 1];
        if (gk + 2 < K) a2 = A[(size_t)gm * K + gk + 2];
        if (gk + 3 < K) a3 = A[(size_t)gm * K + gk + 3];
      }
    }
    int gn = n0 + row;
    if (gn < N) {
      if (gk + 3 < K) {
        float4 v = *(const float4*)&Wt[(size_t)gn * K + gk];
        b0 = v.x; b1 = v.y; b2 = v.z; b3 = v.w;
      } else {
        if (gk + 0 < K) b0 = Wt[(size_t)gn * K + gk + 0];
        if (gk + 1 < K) b1 = Wt[(size_t)gn * K + gk + 1];
        if (gk + 2 < K) b2 = Wt[(size_t)gn * K + gk + 2];
        if (gk + 3 < K) b3 = Wt[(size_t)gn * K + gk + 3];
      }
    }
    As[kk + 0][row] = a0; As[kk + 1][row] = a1; As[kk + 2][row] = a2; As[kk + 3][row] = a3;
    Bs[kk + 0][row] = b0; Bs[kk + 1][row] = b1; Bs[kk + 2][row] = b2; Bs[kk + 3][row] = b3;
    __syncthreads();
#pragma unroll
    for (int k = 0; k < 16; k++) {
      float4 a4 = *(const float4*)&As[k][ty * 4];
      float4 b4 = *(const float4*)&Bs[k][tx * 4];
      c[0][0] = fmaf(a4.x, b4.x, c[0][0]); c[0][1] = fmaf(a4.x, b4.y, c[0][1]);
      c[0][2] = fmaf(a4.x, b4.z, c[0][2]); c[0][3] = fmaf(a4.x, b4.w, c[0][3]);
      c[1][0] = fmaf(a4.y, b4.x, c[1][0]); c[1][1] = fmaf(a4.y, b4.y, c[1][1]);
      c[1][2] = fmaf(a4.y, b4.z, c[1][2]); c[1][3] = fmaf(a4.y, b4.w, c[1][3]);
      c[2][0] = fmaf(a4.z, b4.x, c[2][0]); c[2][1] = fmaf(a4.z, b4.y, c[2][1]);
      c[2][2] = fmaf(a4.z, b4.z, c[2][2]); c[2][3] = fmaf(a4.z, b4.w, c[2][3]);
      c[3][0] = fmaf(a4.w, b4.x, c[3][0]); c[3][1] = fmaf(a4.w, b4.y, c[3][1]);
      c[3][2] = fmaf(a4.w, b4.z, c[3][2]); c[3][3] = fmaf(a4.w, b4.w, c[3][3]);
    }
    __syncthreads();
  }
#pragma unroll
  for (int i = 0; i < 4; i++) {
    int gm = m0 + ty * 4 + i;
    if (gm >= M) continue;
#pragma unroll
    for (int j = 0; j < 4; j++) {
      int gn = n0 + tx * 4 + j;
      if (gn >= N) continue;
      float v = c[i][j];
      if (BIAS) v += bias[gn];
      if (RELU) v = fmaxf(v, 0.f);
      C[(size_t)gm * ldc + gn] = v;
    }
  }
}

// ---------------------------------------------------------------- GRU recurrence
// 20 float4 of whh register-cached as NAMED vars (80 VGPR, fits the 170-reg
// cap a 10-wave block imposes); remaining 30 float4 streamed from L2.

#define GRU_FMA(W4, K4) { \
  float4 h0 = *(const float4*)&h[4 * (K4) + 0][0]; \
  float4 h1 = *(const float4*)&h[4 * (K4) + 1][0]; \
  float4 h2 = *(const float4*)&h[4 * (K4) + 2][0]; \
  float4 h3 = *(const float4*)&h[4 * (K4) + 3][0]; \
  a0 = fmaf((W4).x, h0.x, a0); a1 = fmaf((W4).x, h0.y, a1); \
  a2 = fmaf((W4).x, h0.z, a2); a3 = fmaf((W4).x, h0.w, a3); \
  a0 = fmaf((W4).y, h1.x, a0); a1 = fmaf((W4).y, h1.y, a1); \
  a2 = fmaf((W4).y, h1.z, a2); a3 = fmaf((W4).y, h1.w, a3); \
  a0 = fmaf((W4).z, h2.x, a0); a1 = fmaf((W4).z, h2.y, a1); \
  a2 = fmaf((W4).z, h2.z, a2); a3 = fmaf((W4).z, h2.w, a3); \
  a0 = fmaf((W4).w, h3.x, a0); a1 = fmaf((W4).w, h3.y, a1); \
  a2 = fmaf((W4).w, h3.z, a2); a3 = fmaf((W4).w, h3.w, a3); }

#define WLIST(OP) OP(0) OP(1) OP(2) OP(3) OP(4) OP(5) OP(6) OP(7) OP(8) OP(9) \
  OP(10) OP(11) OP(12) OP(13) OP(14) OP(15) OP(16) OP(17) OP(18) OP(19)

__global__ __launch_bounds__(640, 1) void gru_recur(RecurArgs a) {
  int blk = blockIdx.x;
  const float* __restrict__ gx = a.gx[blk];
  const float4* __restrict__ wp = (const float4*)a.wT[blk];
  const float* __restrict__ bh = a.bh[blk];
  float* __restrict__ outp = a.out[blk];
  const int* lenp = a.len[blk];
  int TT = a.Tl[blk];
  int bwd = a.dir[blk];
  int dirOff = bwd ? 200 : 0;

  __shared__ float h[200][4];
  __shared__ float gh[600][4];
  __shared__ float bhs[600];
  __shared__ int lens[4];
  int tid = threadIdx.x;
  for (int i = tid; i < 800; i += 640) ((float*)h)[i] = 0.f;
  for (int i = tid; i < 600; i += 640) bhs[i] = bh[i];
  if (tid < 4) lens[tid] = lenp[tid];

  int wrow = tid < 600 ? tid : 599;   // clamped, unconditional loads
#define WDECL(i) float4 wc##i = wp[(i) * 600 + wrow];
  WLIST(WDECL)
#undef WDECL
  __syncthreads();
  int maxlen = max(max(lens[0], lens[1]), max(lens[2], lens[3]));

  for (int s = 0; s < maxlen; s++) {
    if (tid < 600) {
      float a0 = 0.f, a1 = 0.f, a2 = 0.f, a3 = 0.f;
#define WUSE(i) GRU_FMA(wc##i, i)
      WLIST(WUSE)
#undef WUSE
#pragma unroll 6
      for (int k4 = 20; k4 < 50; k4++) {
        float4 w4 = wp[k4 * 600 + tid];
        GRU_FMA(w4, k4)
      }
      float bb = bhs[tid];
      gh[tid][0] = a0 + bb; gh[tid][1] = a1 + bb;
      gh[tid][2] = a2 + bb; gh[tid][3] = a3 + bb;
    }
    __syncthreads();
    for (int it = tid; it < 800; it += 640) {
      int i = it >> 2, b = it & 3;
      int Lb = lens[b];
      if (s < Lb) {
        int ta = bwd ? (Lb - 1 - s) : s;
        const float* gxr = gx + (size_t)(b * TT + ta) * 600;
        float r = 1.f / (1.f + expf(-(gxr[i] + gh[i][b])));
        float z = 1.f / (1.f + expf(-(gxr[200 + i] + gh[200 + i][b])));
        float n = tanhf(gxr[400 + i] + r * gh[400 + i][b]);
        float hn = (1.f - z) * n + z * h[i][b];
        h[i][b] = hn;
        outp[(size_t)(b * TT + ta) * 400 + dirOff + i] = hn;
      }
    }
    __syncthreads();
  }
}

// ---------------------------------------------------------------- f16 fragment prep kernels
// Fragment layout (1KB block = 16(m|n) x 32k f16): lane l holds 8 elems at byte l*16.
// elem j: mn = l&15, k = (l>>4)*4 + (j&3) + (j>>2)*16.  Same formula used for all
// operands => k-slot pairing is consistent A vs B (permutation-invariant dot).

__global__ void cvt_lf_frags(const float* __restrict__ lab, const float* __restrict__ gnf,
                             f16* __restrict__ out) {
  int e = blockIdx.x * 256 + threadIdx.x;
  if (e >= 1752 * 13 * 512) return;
  int frag = e >> 9, r = e & 511;
  int l = r >> 3, j = r & 7;
  int nsub = frag / 13, kt = frag - nsub * 13;
  int label = nsub * 16 + (l & 15);
  int k = kt * 32 + ((l >> 4) << 2) + (j & 3) + ((j >> 2) << 4);
  float v = 0.f;
  if (label < NLAB && k < 400)
    v = (k < 200) ? lab[(size_t)label * 200 + k] : gnf[(size_t)label * 200 + k - 200];
  out[e] = (f16)v;
}

__global__ void cvt_x_frags(const float* __restrict__ x, f16* __restrict__ out, int TT) {
  int e = blockIdx.x * 256 + threadIdx.x;
  if (e >= 4 * TT * 13 * 512) return;
  int frag = e >> 9, r = e & 511;
  int l = r >> 3, j = r & 7;
  int kt = frag % 13, bt = frag / 13;
  int tt = bt % TT, b = bt / TT;
  int t = tt * 16 + (l & 15);
  int k = kt * 32 + ((l >> 4) << 2) + (j & 3) + ((j >> 2) << 4);
  float v = (k < 400) ? x[((size_t)b * TT * 16 + t) * 400 + k] : 0.f;
  out[e] = (f16)v;
}

__global__ void cvt_v_frags(const float* __restrict__ xf, f16* __restrict__ out, int KT) {
  int e = blockIdx.x * 256 + threadIdx.x;
  if (e >= 4 * KT * 13 * 2 * 512) return;
  int idx = e >> 9, r = e & 511;
  int l = r >> 3, j = r & 7;
  int hl = idx & 1, rest = idx >> 1;
  int dt = rest % 13, rest2 = rest / 13;
  int kt = rest2 % KT, b = rest2 / KT;
  int t = kt * 32 + ((l >> 4) << 2) + (j & 3) + ((j >> 2) << 4);
  int d = dt * 16 + (l & 15);
  float v = xf[((size_t)b * KT * 32 + t) * XFS + d];
  float hi = (float)(f16)v;
  out[e] = hl ? (f16)((v - hi) * 2048.f) : (f16)v;
}

// ---------------------------------------------------------------- MFMA attention + fc1 + fc2
// Block 256thr = 4 waves = (nh 0..1, hl 0..1); block covers 64 labels, one batch.
// hl splits: logits t-subtiles AND the V hi/lo precision split (lo scaled x2048).
// ab chunks 0..5 online-softmax (unnormalized acc, CR rescale); ti chunk 6 exact.

__global__ __launch_bounds__(256, 2) void attn_mfma(
    const f16* __restrict__ lfF, const f16* __restrict__ xFab, const f16* __restrict__ xFti,
    const f16* __restrict__ vFab, const f16* __restrict__ vFti,
    const float* __restrict__ fc1b, const float* __restrict__ fc2w,
    const float* __restrict__ fc2b, float* __restrict__ outp) {
  __shared__ float SB[2][32][65];
  __shared__ float CRS[2][2][16];
  __shared__ float LIS[2][2][16];

  int tid = threadIdx.x, lane = tid & 63, w = tid >> 6;
  int nh = w >> 1, hl = w & 1;
  int b = blockIdx.y, nt = blockIdx.x;
  int l15 = lane & 15, lg = lane >> 4;

  f32x4 acc[2][13];
#pragma unroll
  for (int ns = 0; ns < 2; ns++)
#pragma unroll
    for (int dt = 0; dt < 13; dt++) acc[ns][dt] = (f32x4){0.f, 0.f, 0.f, 0.f};
  float mrun[4] = {-INFINITY, -INFINITY, -INFINITY, -INFINITY};
  float lrun[4] = {0.f, 0.f, 0.f, 0.f};

  for (int c = 0; c < 7; c++) {
    const bool ti = (c == 6);
    const f16* xb = ti ? xFti + (size_t)b * (4 * 13 * 512)
                       : xFab + ((size_t)(b * 24 + c * 4)) * 13 * 512;
    // ---- logits: this wave covers ns 0..1  x  tsub {2hl, 2hl+1}
    f32x4 S[2][2];
#pragma unroll
    for (int ns = 0; ns < 2; ns++)
#pragma unroll
      for (int ts = 0; ts < 2; ts++) S[ns][ts] = (f32x4){0.f, 0.f, 0.f, 0.f};
#pragma unroll
    for (int kh = 0; kh < 2; kh++) {
      const int kt0 = kh ? 7 : 0;
      const int ktn = kh ? 6 : 7;
      f16x8 la[2][7];
#pragma unroll
      for (int ns = 0; ns < 2; ns++) {
        const f16* lp = lfF + (((size_t)(nt * 4 + nh * 2 + ns)) * 13 + kt0) * 512 + lane * 8;
#pragma unroll
        for (int k = 0; k < 7; k++)
          if (k < ktn) la[ns][k] = *(const f16x8*)(lp + (size_t)k * 512);
      }
#pragma unroll
      for (int ts = 0; ts < 2; ts++) {
        const f16* xp = xb + (((size_t)(hl * 2 + ts)) * 13 + kt0) * 512 + lane * 8;
        f16x8 xa[7];
#pragma unroll
        for (int k = 0; k < 7; k++)
          if (k < ktn) xa[k] = *(const f16x8*)(xp + (size_t)k * 512);
#pragma unroll
        for (int ns = 0; ns < 2; ns++)
#pragma unroll
          for (int k = 0; k < 7; k++)
            if (k < ktn)
              S[ns][ts] = __builtin_amdgcn_mfma_f32_16x16x32_f16(la[ns][k], xa[k], S[ns][ts], 0, 0, 0);
      }
    }
    __syncthreads();  // SB free from previous chunk
#pragma unroll
    for (int ns = 0; ns < 2; ns++)
#pragma unroll
      for (int ts = 0; ts < 2; ts++)
#pragma unroll
        for (int r = 0; r < 4; r++)
          SB[nh][ns * 16 + lg * 4 + r][(hl * 2 + ts) * 16 + l15] = S[ns][ts][r];
    __syncthreads();
    // ---- softmax for ns == hl labels
    {
      float vv[4][4];
#pragma unroll
      for (int r = 0; r < 4; r++)
#pragma unroll
        for (int ts = 0; ts < 4; ts++)
          vv[r][ts] = SB[nh][hl * 16 + lg * 4 + r][ts * 16 + l15];
#pragma unroll
      for (int r = 0; r < 4; r++) {
        float tm = fmaxf(fmaxf(vv[r][0], vv[r][1]), fmaxf(vv[r][2], vv[r][3]));
        tm = fmaxf(tm, __shfl_xor(tm, 1));
        tm = fmaxf(tm, __shfl_xor(tm, 2));
        tm = fmaxf(tm, __shfl_xor(tm, 4));
        tm = fmaxf(tm, __shfl_xor(tm, 8));
        if (!ti) {
          float mn = fmaxf(mrun[r], tm);
          float cr = expf(mrun[r] - mn);
          float s = 0.f;
#pragma unroll
          for (int ts = 0; ts < 4; ts++) { vv[r][ts] = expf(vv[r][ts] - mn); s += vv[r][ts]; }
          s += __shfl_xor(s, 1); s += __shfl_xor(s, 2);
          s += __shfl_xor(s, 4); s += __shfl_xor(s, 8);
          lrun[r] = lrun[r] * cr + s;
          mrun[r] = mn;
#pragma unroll
          for (int ts = 0; ts < 4; ts++)
            SB[nh][hl * 16 + lg * 4 + r][ts * 16 + l15] = vv[r][ts];
          if (l15 == 0) {
            CRS[nh][hl][lg * 4 + r] = cr;
            if (c == 5) LIS[nh][hl][lg * 4 + r] = 1.f / lrun[r];
          }
        } else {
          float s = 0.f;
#pragma unroll
          for (int ts = 0; ts < 4; ts++) { vv[r][ts] = expf(vv[r][ts] - tm); s += vv[r][ts]; }
          s += __shfl_xor(s, 1); s += __shfl_xor(s, 2);
          s += __shfl_xor(s, 4); s += __shfl_xor(s, 8);
          float inv = 1.f / s;
#pragma unroll
          for (int ts = 0; ts < 4; ts++)
            SB[nh][hl * 16 + lg * 4 + r][ts * 16 + l15] = vv[r][ts] * inv;
        }
      }
    }
    __syncthreads();
    // ---- rescale acc
    if (!ti) {
#pragma unroll
      for (int ns = 0; ns < 2; ns++)
#pragma unroll
        for (int r = 0; r < 4; r++) {
          float cr = CRS[nh][ns][lg * 4 + r];
#pragma unroll
          for (int dt = 0; dt < 13; dt++) acc[ns][dt][r] *= cr;
        }
    } else {
#pragma unroll
      for (int ns = 0; ns < 2; ns++)
#pragma unroll
        for (int r = 0; r < 4; r++) {
          float li = LIS[nh][ns][lg * 4 + r];
#pragma unroll
          for (int dt = 0; dt < 13; dt++) acc[ns][dt][r] *= li;
        }
    }
    // ---- P fragments (A operand of PV)
    f16x8 pf[2][2];
#pragma unroll
    for (int ns = 0; ns < 2; ns++)
#pragma unroll
      for (int kt = 0; kt < 2; kt++)
#pragma unroll
        for (int j = 0; j < 8; j++) {
          int col = kt * 32 + (lg << 2) + (j & 3) + ((j >> 2) << 4);
          pf[ns][kt][j] = (f16)SB[nh][ns * 16 + l15][col];
        }
    // ---- PV
#pragma unroll
    for (int dt = 0; dt < 13; dt++)
#pragma unroll
      for (int kt = 0; kt < 2; kt++) {
        const f16* vp = (ti ? vFti + (((size_t)((b * 2 + kt) * 13 + dt)) * 2 + hl) * 512
                            : vFab + (((size_t)((b * 12 + c * 2 + kt) * 13 + dt)) * 2 + hl) * 512)
                        + lane * 8;
        f16x8 vf = *(const f16x8*)vp;
#pragma unroll
        for (int ns = 0; ns < 2; ns++)
          acc[ns][dt] = __builtin_amdgcn_mfma_f32_16x16x32_f16(pf[ns][kt], vf, acc[ns][dt], 0, 0, 0);
      }
  }

  // ---- epilogue: merge hi/lo waves, fc1 bias + leaky, fc2 dot
  float part[2][4] = {{0.f, 0.f, 0.f, 0.f}, {0.f, 0.f, 0.f, 0.f}};
#pragma unroll
  for (int p = 0; p < 4; p++) {
    const int dt0 = p * 4;
    const int dtn = (p == 3) ? 1 : 4;
    __syncthreads();
    if (hl) {
#pragma unroll
      for (int ns = 0; ns < 2; ns++)
#pragma unroll
        for (int q = 0; q < 4; q++)
          if (q < dtn)
#pragma unroll
            for (int r = 0; r < 4; r++)
              SB[nh][ns * 16 + lg * 4 + r][q * 16 + l15] = acc[ns][dt0 + q][r];
    }
    __syncthreads();
    if (!hl) {
#pragma unroll
      for (int ns = 0; ns < 2; ns++)
#pragma unroll
        for (int q = 0; q < 4; q++)
          if (q < dtn)
#pragma unroll
            for (int r = 0; r < 4; r++) {
              int d = (dt0 + q) * 16 + l15;
              float y = acc[ns][dt0 + q][r] +
                        SB[nh][ns * 16 + lg * 4 + r][q * 16 + l15] * (1.f / 2048.f);
              if (d < 200) {
                y += fc1b[d];
                y = y >= 0.f ? y : 0.2f * y;
                part[ns][r] = fmaf(y, fc2w[d], part[ns][r]);
              }
            }
    }
  }
  if (!hl) {
#pragma unroll
    for (int ns = 0; ns < 2; ns++)
#pragma unroll
      for (int r = 0; r < 4; r++) {
        float s = part[ns][r];
        s += __shfl_xor(s, 1); s += __shfl_xor(s, 2);
        s += __shfl_xor(s, 4); s += __shfl_xor(s, 8);
        part[ns][r] = s;
      }
    if (l15 == 0) {
      float f2b = fc2b[0];
#pragma unroll
      for (int ns = 0; ns < 2; ns++)
#pragma unroll
        for (int r = 0; r < 4; r++) {
          int label = nt * 64 + nh * 32 + ns * 16 + lg * 4 + r;
          if (label < NLAB) {
            float y = part[ns][r] + f2b;
            y = y >= 0.f ? y : 0.2f * y;
            outp[(size_t)b * NLAB + label] = y;
          }
        }
    }
  }
}

// ---------------------------------------------------------------- launch

extern "C" void kernel_launch(void* const* d_in, const int* in_sizes, int n_in,
                              void* d_out, int out_size, void* d_ws, size_t ws_size,
                              hipStream_t stream) {
  (void)in_sizes; (void)n_in; (void)out_size; (void)ws_size;
  const int* tok_ab = (const int*)d_in[0];
  const int* tok_ti = (const int*)d_in[1];
  const int* len_ab = (const int*)d_in[2];
  const int* len_ti = (const int*)d_in[3];
  const int* esrc = (const int*)d_in[4];
  const int* edst = (const int*)d_in[5];
  const float* gnf = (const float*)d_in[6];
  const float* emb = (const float*)d_in[7];
  const float* wih0f = (const float*)d_in[8],  *whh0f = (const float*)d_in[9];
  const float* bih0f = (const float*)d_in[10], *bhh0f = (const float*)d_in[11];
  const float* wih0b = (const float*)d_in[12], *whh0b = (const float*)d_in[13];
  const float* bih0b = (const float*)d_in[14], *bhh0b = (const float*)d_in[15];
  const float* wih1f = (const float*)d_in[16], *whh1f = (const float*)d_in[17];
  const float* bih1f = (const float*)d_in[18], *bhh1f = (const float*)d_in[19];
  const float* wih1b = (const float*)d_in[20], *whh1b = (const float*)d_in[21];
  const float* bih1b = (const float*)d_in[22], *bhh1b = (const float*)d_in[23];
  const float* gw1 = (const float*)d_in[24], *gb1 = (const float*)d_in[25];
  const float* gw2 = (const float*)d_in[26], *gb2 = (const float*)d_in[27];
  const float* fc1w = (const float*)d_in[28], *fc1b = (const float*)d_in[29];
  const float* fc2w = (const float*)d_in[30], *fc2b = (const float*)d_in[31];

  float* W = (float*)d_ws;
  float* agg  = W;             // [0 .. 5.6M)
  float* hbuf = W + 5600000;   // [5.6M .. 11.2M)   dead after GCN
  float* lab  = W + 11200000;  // [11.2M .. 16.8M)
  // overlay (dead-GCN regions):
  float* whhT   = W;            // 480,000
  float* x0ab   = W + 480000;   // 307,200
  float* x0ti   = W + 787200;   // 51,200
  float* gxfab  = W + 838400;   // 921,600 (later: frag arrays)
  float* gxbab  = W + 1760000;  // 921,600
  float* gxfti  = W + 2681600;  // 153,600
  float* gxbti  = W + 2835200;  // 153,600
  float* out0ab = W + 2988800;  // 614,400
  float* out0ti = W + 3603200;  // 102,400
  float* out1ab = W + 3705600;  // 614,400
  float* out1ti = W + 4320000;  // 102,400
  float* xf1ab  = W + 4422400;  // 344,064 (1536 x 224)
  float* xf1ti  = W + 4766464;  // 57,344  (256 x 224)
  // f16 fragment arrays (counts in f32 slots; 2 f16 per slot)
  f16* xFab = (f16*)(W + 838400);    // 638,976 f16 -> 319,488 slots (overlays gx, post-GRU)
  f16* xFti = (f16*)(W + 1157888);   // 106,496 f16 ->  53,248
  f16* vFab = (f16*)(W + 1211136);   // 638,976 f16 -> 319,488
  f16* vFti = (f16*)(W + 1530624);   // 106,496 f16 ->  53,248
  f16* lfF  = (f16*)(W + 4850000);   // 11,661,312 f16 -> 5,830,656 (overlays agg tail + hbuf)

  int gatherBlocks = NEDGE / 4;
  dim3 gGcn(4, 438);

  // ---- GCN ----
  hipMemsetAsync(agg, 0, 5600000 * sizeof(float), stream);
  gcn_gather<<<gatherBlocks, 256, 0, stream>>>(gnf, esrc, edst, agg);
  gemm_nt<1, 1><<<gGcn, 256, 0, stream>>>(agg, gw1, gb1, hbuf, NLAB, 200, 200, 200);
  hipMemsetAsync(agg, 0, 5600000 * sizeof(float), stream);
  gcn_gather<<<gatherBlocks, 256, 0, stream>>>(hbuf, esrc, edst, agg);
  gemm_nt<0, 1><<<gGcn, 256, 0, stream>>>(agg, gw2, gb2, lab, NLAB, 200, 200, 200);

  // ---- label-feature fragments (hbuf dead from here) ----
  cvt_lf_frags<<<(1752 * 13 * 512 + 255) / 256, 256, 0, stream>>>(lab, gnf, lfF);

  // ---- GRU prep ----
  pack_whh<<<(120000 + 255) / 256, 256, 0, stream>>>(whh0f, whhT + 0);
  pack_whh<<<(120000 + 255) / 256, 256, 0, stream>>>(whh0b, whhT + 120000);
  pack_whh<<<(120000 + 255) / 256, 256, 0, stream>>>(whh1f, whhT + 240000);
  pack_whh<<<(120000 + 255) / 256, 256, 0, stream>>>(whh1b, whhT + 360000);
  embed_gather<<<(1536 * 50 + 255) / 256, 256, 0, stream>>>(tok_ab, emb, x0ab, 1536);
  embed_gather<<<(256 * 50 + 255) / 256, 256, 0, stream>>>(tok_ti, emb, x0ti, 256);
  hipMemsetAsync(out0ab, 0, (size_t)1433600 * sizeof(float), stream);
  hipMemsetAsync(xf1ab, 0, (size_t)(344064 + 57344) * sizeof(float), stream);

  dim3 gGxAb(10, 24), gGxTi(10, 4);
  gemm_nt<0, 1><<<gGxAb, 256, 0, stream>>>(x0ab, wih0f, bih0f, gxfab, 1536, 600, 200, 600);
  gemm_nt<0, 1><<<gGxAb, 256, 0, stream>>>(x0ab, wih0b, bih0b, gxbab, 1536, 600, 200, 600);
  gemm_nt<0, 1><<<gGxTi, 256, 0, stream>>>(x0ti, wih0f, bih0f, gxfti, 256, 600, 200, 600);
  gemm_nt<0, 1><<<gGxTi, 256, 0, stream>>>(x0ti, wih0b, bih0b, gxbti, 256, 600, 200, 600);

  RecurArgs r0;
  r0.gx[0] = gxfab; r0.gx[1] = gxbab; r0.gx[2] = gxfti; r0.gx[3] = gxbti;
  r0.wT[0] = whhT; r0.wT[1] = whhT + 120000; r0.wT[2] = whhT; r0.wT[3] = whhT + 120000;
  r0.bh[0] = bhh0f; r0.bh[1] = bhh0b; r0.bh[2] = bhh0f; r0.bh[3] = bhh0b;
  r0.out[0] = out0ab; r0.out[1] = out0ab; r0.out[2] = out0ti; r0.out[3] = out0ti;
  r0.len[0] = len_ab; r0.len[1] = len_ab; r0.len[2] = len_ti; r0.len[3] = len_ti;
  r0.Tl[0] = 384; r0.Tl[1] = 384; r0.Tl[2] = 64; r0.Tl[3] = 64;
  r0.dir[0] = 0; r0.dir[1] = 1; r0.dir[2] = 0; r0.dir[3] = 1;
  gru_recur<<<4, 640, 0, stream>>>(r0);

  gemm_nt<0, 1><<<gGxAb, 256, 0, stream>>>(out0ab, wih1f, bih1f, gxfab, 1536, 600, 400, 600);
  gemm_nt<0, 1><<<gGxAb, 256, 0, stream>>>(out0ab, wih1b, bih1b, gxbab, 1536, 600, 400, 600);
  gemm_nt<0, 1><<<gGxTi, 256, 0, stream>>>(out0ti, wih1f, bih1f, gxfti, 256, 600, 400, 600);
  gemm_nt<0, 1><<<gGxTi, 256, 0, stream>>>(out0ti, wih1b, bih1b, gxbti, 256, 600, 400, 600);

  RecurArgs r1 = r0;
  r1.wT[0] = whhT + 240000; r1.wT[1] = whhT + 360000;
  r1.wT[2] = whhT + 240000; r1.wT[3] = whhT + 360000;
  r1.bh[0] = bhh1f; r1.bh[1] = bhh1b; r1.bh[2] = bhh1f; r1.bh[3] = bhh1b;
  r1.out[0] = out1ab; r1.out[1] = out1ab; r1.out[2] = out1ti; r1.out[3] = out1ti;
  gru_recur<<<4, 640, 0, stream>>>(r1);

  // ---- xf1 = out1 @ fc1^T ----
  gemm_nt<0, 0><<<dim3(4, 24), 256, 0, stream>>>(out1ab, fc1w, nullptr, xf1ab, 1536, 200, 400, XFS);
  gemm_nt<0, 0><<<dim3(4, 4), 256, 0, stream>>>(out1ti, fc1w, nullptr, xf1ti, 256, 200, 400, XFS);

  // ---- x / V fragments (gx regions dead from here) ----
  cvt_x_frags<<<(4 * 24 * 13 * 512 + 255) / 256, 256, 0, stream>>>(out1ab, xFab, 24);
  cvt_x_frags<<<(4 * 4 * 13 * 512 + 255) / 256, 256, 0, stream>>>(out1ti, xFti, 4);
  cvt_v_frags<<<(4 * 12 * 13 * 2 * 512 + 255) / 256, 256, 0, stream>>>(xf1ab, vFab, 12);
  cvt_v_frags<<<(4 * 2 * 13 * 2 * 512 + 255) / 256, 256, 0, stream>>>(xf1ti, vFti, 2);

  // ---- fused MFMA attention ----
  attn_mfma<<<dim3(438, 4), 256, 0, stream>>>(
      lfF, xFab, xFti, vFab, vFti, fc1b, fc2w, fc2b, (float*)d_out);
}